// Round 5
// baseline (388.119 us; speedup 1.0000x reference)
//
#include <hip/hip_runtime.h>

#define HIDDEN 2048
#define NB 64
#define NT 512
#define NK 49

typedef __attribute__((ext_vector_type(4))) float f32x4;
typedef __attribute__((ext_vector_type(8))) short short8;

__device__ __forceinline__ unsigned cvtpk_bf16(float a, float b) {
    unsigned r;
    asm("v_cvt_pk_bf16_f32 %0, %1, %2" : "=v"(r) : "v"(a), "v"(b));
    return r;
}

// scalar RNE f32->bf16 (convert kernel only; not perf-critical)
__device__ __forceinline__ unsigned short f2bf(float x) {
    union { float f; unsigned u; } v; v.f = x;
    unsigned r = v.u + 0x7FFF + ((v.u >> 16) & 1);
    return (unsigned short)(r >> 16);
}

// ---------------------------------------------------------------------------
// Kernel 0: convert + swizzle W{g,s,v} (fp32 [49][2048]) into MFMA B-fragment
// order, padded to 64 cols with zeros.  (unchanged, proven)
// ---------------------------------------------------------------------------
__global__ __launch_bounds__(256) void convert_w(
    const float* __restrict__ Wg, const float* __restrict__ Ws,
    const float* __restrict__ Wv, unsigned short* __restrict__ Wf)
{
    int tau = blockIdx.x * 256 + threadIdx.x;      // 0..49151
    int m   = tau >> 14;
    int rem = tau & 16383;
    int c   = rem >> 12;
    int s   = (rem >> 6) & 63;
    int l   = rem & 63;
    int col = c * 16 + (l & 15);
    int k0  = s * 32 + ((l >> 4) << 3);

    const float* W = (m == 0) ? Wg : (m == 1) ? Ws : Wv;
    unsigned short out[8];
    if (col < NK) {
        const float* p = W + (size_t)col * HIDDEN + k0;
        #pragma unroll
        for (int j = 0; j < 8; j++) out[j] = f2bf(p[j]);
    } else {
        #pragma unroll
        for (int j = 0; j < 8; j++) out[j] = 0;
    }
    unsigned short* dst = Wf + (size_t)tau * 8;
    #pragma unroll
    for (int j = 0; j < 8; j++) dst[j] = out[j];
}

// ---------------------------------------------------------------------------
// Kernel 1 v3: MFMA GEMM, no LDS, named-variable ping-pong double buffer.
// Inner math is byte-identical to the proven R2 body; only the load schedule
// changed. No arrays, no modulo indexing, #pragma unroll 1 on the main loop.
// Per body (4 iters): issue Q loads -> compute P(2) -> issue P refill ->
// compute Q(2). >=12 loads always in flight per wave.
// ---------------------------------------------------------------------------
#define LOADA(A0, A1, idx) \
    { A0 = *(const float4*)(ap + (idx) * 32); \
      A1 = *(const float4*)(ap + (idx) * 32 + 4); }

#define LOADB(B0, B1, B2, B3, idx) \
    { B0 = bp[(0 * 64 + (idx)) * 64]; \
      B1 = bp[(1 * 64 + (idx)) * 64]; \
      B2 = bp[(2 * 64 + (idx)) * 64]; \
      B3 = bp[(3 * 64 + (idx)) * 64]; }

#define COMPUTE(A0, A1, B0, B1, B2, B3) \
    { union { short8 v; unsigned u[4]; } a_; \
      a_.u[0] = cvtpk_bf16(A0.x, A0.y); \
      a_.u[1] = cvtpk_bf16(A0.z, A0.w); \
      a_.u[2] = cvtpk_bf16(A1.x, A1.y); \
      a_.u[3] = cvtpk_bf16(A1.z, A1.w); \
      acc0 = __builtin_amdgcn_mfma_f32_16x16x32_bf16(a_.v, B0, acc0, 0, 0, 0); \
      acc1 = __builtin_amdgcn_mfma_f32_16x16x32_bf16(a_.v, B1, acc1, 0, 0, 0); \
      acc2 = __builtin_amdgcn_mfma_f32_16x16x32_bf16(a_.v, B2, acc2, 0, 0, 0); \
      acc3 = __builtin_amdgcn_mfma_f32_16x16x32_bf16(a_.v, B3, acc3, 0, 0, 0); }

__global__ __launch_bounds__(256) void gemm_mfma(
    const float* __restrict__ h, const float* __restrict__ s,
    const float* __restrict__ V, const unsigned short* __restrict__ Wf,
    float* __restrict__ pg, float* __restrict__ ps, float* __restrict__ pv)
{
    int w = threadIdx.x >> 6, lane = threadIdx.x & 63;
    int gw = blockIdx.x * 4 + w;

    const float* A; float* C; int rowBase; const unsigned short* wf;
    if (gw < 2048)      { A = h; C = pg; rowBase = gw * 16;          wf = Wf; }
    else if (gw < 4096) { A = s; C = ps; rowBase = (gw - 2048) * 16; wf = Wf + (size_t)16384 * 8; }
    else                { A = V; C = pv; rowBase = (gw - 4096) * 16; wf = Wf + (size_t)32768 * 8; }

    const float* ap = A + (size_t)(rowBase + (lane & 15)) * HIDDEN + ((lane >> 4) << 3);
    const short8* bp = (const short8*)(wf + (size_t)lane * 8);

    f32x4 acc0 = {0.f, 0.f, 0.f, 0.f};
    f32x4 acc1 = acc0, acc2 = acc0, acc3 = acc0;

    // P group (iters st, st+1), Q group (iters st+2, st+3) — all named.
    float4 pa0_0, pa1_0, pa0_1, pa1_1;
    short8 pb0_0, pb1_0, pb2_0, pb3_0, pb0_1, pb1_1, pb2_1, pb3_1;
    float4 qa0_0, qa1_0, qa0_1, qa1_1;
    short8 qb0_0, qb1_0, qb2_0, qb3_0, qb0_1, qb1_1, qb2_1, qb3_1;

    LOADA(pa0_0, pa1_0, 0)
    LOADA(pa0_1, pa1_1, 1)
    LOADB(pb0_0, pb1_0, pb2_0, pb3_0, 0)
    LOADB(pb0_1, pb1_1, pb2_1, pb3_1, 1)

    #pragma unroll 1
    for (int st = 0; st < 64; st += 4) {
        // issue Q loads (iters st+2, st+3) — always in range (max 62,63)
        LOADA(qa0_0, qa1_0, st + 2)
        LOADA(qa0_1, qa1_1, st + 3)
        LOADB(qb0_0, qb1_0, qb2_0, qb3_0, st + 2)
        LOADB(qb0_1, qb1_1, qb2_1, qb3_1, st + 3)

        // compute P (iters st, st+1)
        COMPUTE(pa0_0, pa1_0, pb0_0, pb1_0, pb2_0, pb3_0)
        COMPUTE(pa0_1, pa1_1, pb0_1, pb1_1, pb2_1, pb3_1)

        // refill P with iters st+4, st+5
        if (st + 4 < 64) {
            LOADA(pa0_0, pa1_0, st + 4)
            LOADA(pa0_1, pa1_1, st + 5)
            LOADB(pb0_0, pb1_0, pb2_0, pb3_0, st + 4)
            LOADB(pb0_1, pb1_1, pb2_1, pb3_1, st + 5)
        }

        // compute Q (iters st+2, st+3)
        COMPUTE(qa0_0, qa1_0, qb0_0, qb1_0, qb2_0, qb3_0)
        COMPUTE(qa0_1, qa1_1, qb0_1, qb1_1, qb2_1, qb3_1)
    }

    // C/D layout (verified m89): col = lane&15, row = (lane>>4)*4 + reg
    int colb  = lane & 15;
    int rquad = (lane >> 4) << 2;
    float* crow = C + (size_t)(rowBase + rquad) * NK + colb;
    #pragma unroll
    for (int r = 0; r < 4; r++) {
        crow[(size_t)r * NK + 0]  = acc0[r];
        crow[(size_t)r * NK + 16] = acc1[r];
        crow[(size_t)r * NK + 32] = acc2[r];
    }
    if (colb == 0) {
        #pragma unroll
        for (int r = 0; r < 4; r++) crow[(size_t)r * NK + 48] = acc3[r];
    }
}

// fast tanh: 1 - 2/(exp(2x)+1); safe at +-inf of exp
__device__ __forceinline__ float ftanh(float x) {
    float e = __expf(2.f * x);
    return 1.f - 2.f * __builtin_amdgcn_rcpf(e + 1.f);
}

// ---------------------------------------------------------------------------
// Kernel 2: per-(b,t) scores + softmaxes. One wave per row (b,t). (unchanged)
// ---------------------------------------------------------------------------
__global__ __launch_bounds__(256) void zab_kernel(
    const float* __restrict__ pg, const float* __restrict__ ps,
    const float* __restrict__ pv, const float* __restrict__ Wh,
    float* __restrict__ alpha, float* __restrict__ beta)
{
    int w = threadIdx.x >> 6, lane = threadIdx.x & 63;
    int row = blockIdx.x * 4 + w;        // 0..32767
    int b = row >> 9;

    const float* pgrow = pg + (size_t)row * NK;
    const float* psrow = ps + (size_t)row * NK;

    // phase A: z_ext
    float va = 0.f;
    if (lane < NK)
        va = ftanh(psrow[lane] + pgrow[lane]) * Wh[lane];
    float z_ext = va;
    #pragma unroll
    for (int off = 32; off; off >>= 1) z_ext += __shfl_xor(z_ext, off);

    // phase B: z[k]
    float z = -1e30f;
    if (lane < NK) {
        const float* pvrow = pv + ((size_t)b * NK + lane) * NK;
        float acc = 0.f;
        for (int j = 0; j < NK; j++)
            acc = fmaf(ftanh(pvrow[j] + pgrow[j]), Wh[j], acc);
        z = acc;
    }

    // softmax over k (49)
    float m = z;
    #pragma unroll
    for (int off = 32; off; off >>= 1) m = fmaxf(m, __shfl_xor(m, off));
    float p = (lane < NK) ? __expf(z - m) : 0.f;
    float ssum = p;
    #pragma unroll
    for (int off = 32; off; off >>= 1) ssum += __shfl_xor(ssum, off);
    float a = p * __builtin_amdgcn_rcpf(ssum);

    if (lane < NK)
        alpha[(size_t)row * NK + lane] = a;

    // extended softmax -> beta
    float me = fmaxf(m, z_ext);
    float se = ssum * __expf(m - me) + __expf(z_ext - me);
    float bet = __expf(z_ext - me) * __builtin_amdgcn_rcpf(se);
    if (lane == 0) beta[row] = bet;
}

// ---------------------------------------------------------------------------
// Kernel 3: c_hat = beta*sent + (1-beta)*(alpha @ V). (unchanged)
// ---------------------------------------------------------------------------
__global__ __launch_bounds__(256) void chat_kernel(
    const float* __restrict__ V, const float* __restrict__ sent,
    const float* __restrict__ alpha, const float* __restrict__ beta,
    float* __restrict__ chat)
{
    int d0 = blockIdx.x * 128;
    int t0 = blockIdx.y * 32;
    int b  = blockIdx.z;

    __shared__ float alpha_s[NK][36];   // transposed: [k][t], stride 36
    __shared__ float beta_s[32];

    int tid = threadIdx.x;

    const float* arow = alpha + ((size_t)b * NT + t0) * NK;  // 1568 contiguous
    for (int i = tid; i < 32 * NK; i += 256) {
        int t = i / NK, k = i - t * NK;
        alpha_s[k][t] = arow[i];
    }
    if (tid < 32) beta_s[tid] = beta[(size_t)b * NT + t0 + tid];
    __syncthreads();

    int tx = tid & 31;          // d-group: d = d0 + tx*4
    int ty = tid >> 5;          // t-group: t = t0 + ty*4 + i

    const float* vp = V + (size_t)b * NK * HIDDEN + d0 + tx * 4;

    float4 acc[4];
    #pragma unroll
    for (int i = 0; i < 4; i++) acc[i] = make_float4(0.f, 0.f, 0.f, 0.f);

    #pragma unroll 7
    for (int k = 0; k < NK; k++) {
        float4 vv = *(const float4*)(vp + (size_t)k * HIDDEN);
        float4 a4 = *(const float4*)&alpha_s[k][ty * 4];
        acc[0].x = fmaf(a4.x, vv.x, acc[0].x);
        acc[0].y = fmaf(a4.x, vv.y, acc[0].y);
        acc[0].z = fmaf(a4.x, vv.z, acc[0].z);
        acc[0].w = fmaf(a4.x, vv.w, acc[0].w);
        acc[1].x = fmaf(a4.y, vv.x, acc[1].x);
        acc[1].y = fmaf(a4.y, vv.y, acc[1].y);
        acc[1].z = fmaf(a4.y, vv.z, acc[1].z);
        acc[1].w = fmaf(a4.y, vv.w, acc[1].w);
        acc[2].x = fmaf(a4.z, vv.x, acc[2].x);
        acc[2].y = fmaf(a4.z, vv.y, acc[2].y);
        acc[2].z = fmaf(a4.z, vv.z, acc[2].z);
        acc[2].w = fmaf(a4.z, vv.w, acc[2].w);
        acc[3].x = fmaf(a4.w, vv.x, acc[3].x);
        acc[3].y = fmaf(a4.w, vv.y, acc[3].y);
        acc[3].z = fmaf(a4.w, vv.z, acc[3].z);
        acc[3].w = fmaf(a4.w, vv.w, acc[3].w);
    }

    #pragma unroll
    for (int i = 0; i < 4; i++) {
        int t = ty * 4 + i;
        float bt = beta_s[t];
        const float* sp = sent + ((size_t)b * NT + t0 + t) * HIDDEN + d0 + tx * 4;
        float*       op = chat + ((size_t)b * NT + t0 + t) * HIDDEN + d0 + tx * 4;
        float4 sv = *(const float4*)sp;
        float4 o;
        o.x = fmaf(bt, sv.x, (1.f - bt) * acc[i].x);
        o.y = fmaf(bt, sv.y, (1.f - bt) * acc[i].y);
        o.z = fmaf(bt, sv.z, (1.f - bt) * acc[i].z);
        o.w = fmaf(bt, sv.w, (1.f - bt) * acc[i].w);
        *(float4*)op = o;
    }
}

extern "C" void kernel_launch(void* const* d_in, const int* in_sizes, int n_in,
                              void* d_out, int out_size, void* d_ws, size_t ws_size,
                              hipStream_t stream)
{
    const float* V    = (const float*)d_in[0];
    const float* h_t  = (const float*)d_in[1];
    const float* sent = (const float*)d_in[2];
    const float* Wv   = (const float*)d_in[3];
    const float* Wg   = (const float*)d_in[4];
    const float* Ws   = (const float*)d_in[5];
    const float* Wh   = (const float*)d_in[6];

    float* out   = (float*)d_out;
    float* chat  = out;                                   // B*T*HIDDEN
    float* alpha = out + (size_t)NB * NT * HIDDEN;        // B*T*K
    float* beta  = alpha + (size_t)NB * NT * NK;          // B*T

    float* ws = (float*)d_ws;
    float* pg = ws;                                       // 32768*49
    float* ps = pg + (size_t)NB * NT * NK;                // 32768*49
    float* pv = ps + (size_t)NB * NT * NK;                // 3136*49
    unsigned short* Wf = (unsigned short*)(pv + (size_t)NB * NK * NK); // 3*16384*8 bf16

    convert_w<<<192, 256, 0, stream>>>(Wg, Ws, Wv, Wf);
    gemm_mfma<<<1073, 256, 0, stream>>>(h_t, sent, V, Wf, pg, ps, pv);
    zab_kernel<<<(NB * NT) / 4, 256, 0, stream>>>(pg, ps, pv, Wh, alpha, beta);
    chat_kernel<<<dim3(HIDDEN / 128, NT / 32, NB), 256, 0, stream>>>(V, sent, alpha, beta, chat);
}

// Round 6
// 351.660 us; speedup vs baseline: 1.1037x; 1.1037x over previous
//
#include <hip/hip_runtime.h>

#define HIDDEN 2048
#define NB 64
#define NT 512
#define NK 49

typedef __attribute__((ext_vector_type(4))) float f32x4;
typedef __attribute__((ext_vector_type(8))) short short8;

__device__ __forceinline__ unsigned cvtpk_bf16(float a, float b) {
    unsigned r;
    asm("v_cvt_pk_bf16_f32 %0, %1, %2" : "=v"(r) : "v"(a), "v"(b));
    return r;
}

// scalar RNE f32->bf16 (convert kernel only; not perf-critical)
__device__ __forceinline__ unsigned short f2bf(float x) {
    union { float f; unsigned u; } v; v.f = x;
    unsigned r = v.u + 0x7FFF + ((v.u >> 16) & 1);
    return (unsigned short)(r >> 16);
}

// ---------------------------------------------------------------------------
// Kernel 0 v2: convert + swizzle W{g,s,v} (fp32 [49][2048]) into MFMA
// B-fragment order, REORDERED so a K-chunk is contiguous:
//   index tau = ((m*64 + st)*4 + c)*64 + lane   (8 bf16 = 16B per entry)
//   data = W_m[c*16 + (lane&15)][ st*32 + (lane>>4)*8 + j ]   (0 if col>=49)
// ---------------------------------------------------------------------------
__global__ __launch_bounds__(256) void convert_w(
    const float* __restrict__ Wg, const float* __restrict__ Ws,
    const float* __restrict__ Wv, unsigned short* __restrict__ Wf)
{
    int tau = blockIdx.x * 256 + threadIdx.x;      // 0..49151
    int m   = tau >> 14;
    int rem = tau & 16383;
    int st  = rem >> 8;
    int c   = (rem >> 6) & 3;
    int l   = rem & 63;
    int col = c * 16 + (l & 15);
    int k0  = st * 32 + ((l >> 4) << 3);

    const float* W = (m == 0) ? Wg : (m == 1) ? Ws : Wv;
    unsigned short out[8];
    if (col < NK) {
        const float* p = W + (size_t)col * HIDDEN + k0;
        #pragma unroll
        for (int j = 0; j < 8; j++) out[j] = f2bf(p[j]);
    } else {
        #pragma unroll
        for (int j = 0; j < 8; j++) out[j] = 0;
    }
    unsigned short* dst = Wf + (size_t)tau * 8;
    #pragma unroll
    for (int j = 0; j < 8; j++) dst[j] = out[j];
}

// ---------------------------------------------------------------------------
// Kernel 1 v4: MFMA GEMM, B staged in LDS once per block (was 4x per wave
// through L1/L2). Block = 4 waves = 64 rows; wave w owns rows w*16..w*16+15,
// all 64 cols. K-chunk = 4 st (k=128) = 16 KB of B, double-buffered (32 KB).
// Reg-staged B (T14): load chunk+2 early, ds_write chunk+1 at chunk top
// (writers touch nxt, readers cur -> one barrier per chunk).
// A: named-register refill-after-use, distance ~4 iters + barrier.
// ---------------------------------------------------------------------------
__global__ __launch_bounds__(256) void gemm_mfma(
    const float* __restrict__ h, const float* __restrict__ s,
    const float* __restrict__ V, const unsigned short* __restrict__ Wf,
    float* __restrict__ pg, float* __restrict__ ps, float* __restrict__ pv)
{
    int w = threadIdx.x >> 6, lane = threadIdx.x & 63;
    int blk = blockIdx.x;

    const float* A; float* C; int rowBase; const unsigned short* wfm;
    if (blk < 512)       { A = h; C = pg; rowBase = blk * 64;          wfm = Wf; }
    else if (blk < 1024) { A = s; C = ps; rowBase = (blk - 512) * 64;  wfm = Wf + (size_t)16384 * 8; }
    else                 { A = V; C = pv; rowBase = (blk - 1024) * 64; wfm = Wf + (size_t)32768 * 8; }

    // wave w's A rows
    const float* ap = A + (size_t)(rowBase + w * 16 + (lane & 15)) * HIDDEN + ((lane >> 4) << 3);
    const short8* wfp = (const short8*)wfm;   // short8 idx = (st*4 + c)*64 + lane

    __shared__ short8 lb[2][1024];            // 2 x 16 KB chunk buffers
    short8* lbp0 = &lb[0][0];
    short8* lbp1 = &lb[1][0];
    int q = w * 4;                            // this wave's 4 staging slices

    f32x4 acc0 = {0.f, 0.f, 0.f, 0.f};
    f32x4 acc1 = acc0, acc2 = acc0, acc3 = acc0;

    float4 a0_0, a0_1, a1_0, a1_1, a2_0, a2_1, a3_0, a3_1;  // current-chunk A
    short8 bs0, bs1, bs2, bs3;                               // B staging regs

#define LOADBS(ch) { \
    bs0 = wfp[(ch) * 1024 + (q + 0) * 64 + lane]; \
    bs1 = wfp[(ch) * 1024 + (q + 1) * 64 + lane]; \
    bs2 = wfp[(ch) * 1024 + (q + 2) * 64 + lane]; \
    bs3 = wfp[(ch) * 1024 + (q + 3) * 64 + lane]; }

#define WRITEBS(lbp) { \
    lbp[(q + 0) * 64 + lane] = bs0; \
    lbp[(q + 1) * 64 + lane] = bs1; \
    lbp[(q + 2) * 64 + lane] = bs2; \
    lbp[(q + 3) * 64 + lane] = bs3; }

#define LOADA2(A0, A1, gst) { \
    A0 = *(const float4*)(ap + (gst) * 32); \
    A1 = *(const float4*)(ap + (gst) * 32 + 4); }

#define STEP(lbp, sti, Aa, Ab, rgst, dorf) { \
    union { short8 v; unsigned u[4]; } a_; \
    a_.u[0] = cvtpk_bf16(Aa.x, Aa.y); \
    a_.u[1] = cvtpk_bf16(Aa.z, Aa.w); \
    a_.u[2] = cvtpk_bf16(Ab.x, Ab.y); \
    a_.u[3] = cvtpk_bf16(Ab.z, Ab.w); \
    short8 b0 = lbp[((sti) * 4 + 0) * 64 + lane]; \
    short8 b1 = lbp[((sti) * 4 + 1) * 64 + lane]; \
    short8 b2 = lbp[((sti) * 4 + 2) * 64 + lane]; \
    short8 b3 = lbp[((sti) * 4 + 3) * 64 + lane]; \
    if (dorf) { LOADA2(Aa, Ab, rgst) } \
    acc0 = __builtin_amdgcn_mfma_f32_16x16x32_bf16(a_.v, b0, acc0, 0, 0, 0); \
    acc1 = __builtin_amdgcn_mfma_f32_16x16x32_bf16(a_.v, b1, acc1, 0, 0, 0); \
    acc2 = __builtin_amdgcn_mfma_f32_16x16x32_bf16(a_.v, b2, acc2, 0, 0, 0); \
    acc3 = __builtin_amdgcn_mfma_f32_16x16x32_bf16(a_.v, b3, acc3, 0, 0, 0); }

    // prologue: chunk0 B -> LDS buf0; A sts 0..3; chunk1 B -> regs
    LOADBS(0)
    LOADA2(a0_0, a0_1, 0)
    LOADA2(a1_0, a1_1, 1)
    LOADA2(a2_0, a2_1, 2)
    LOADA2(a3_0, a3_1, 3)
    WRITEBS(lbp0)
    LOADBS(1)
    __syncthreads();

    #pragma unroll 1
    for (int ch = 0; ch < 16; ch++) {
        short8* cur = (ch & 1) ? lbp1 : lbp0;
        short8* nxt = (ch & 1) ? lbp0 : lbp1;
        if (ch < 15) { WRITEBS(nxt) }     // B for ch+1 (regs loaded 1 chunk ago)
        if (ch < 14) { LOADBS(ch + 2) }   // issue B loads for ch+2
        bool rf = ch < 15;
        int g = (ch + 1) * 4;
        STEP(cur, 0, a0_0, a0_1, g + 0, rf)
        STEP(cur, 1, a1_0, a1_1, g + 1, rf)
        STEP(cur, 2, a2_0, a2_1, g + 2, rf)
        STEP(cur, 3, a3_0, a3_1, g + 3, rf)
        __syncthreads();
    }

#undef LOADBS
#undef WRITEBS
#undef LOADA2
#undef STEP

    // C/D layout (verified m89): col = lane&15, row = (lane>>4)*4 + reg
    int colb  = lane & 15;
    int rquad = (lane >> 4) << 2;
    float* crow = C + (size_t)(rowBase + w * 16 + rquad) * NK + colb;
    #pragma unroll
    for (int r = 0; r < 4; r++) {
        crow[(size_t)r * NK + 0]  = acc0[r];
        crow[(size_t)r * NK + 16] = acc1[r];
        crow[(size_t)r * NK + 32] = acc2[r];
    }
    if (colb == 0) {
        #pragma unroll
        for (int r = 0; r < 4; r++) crow[(size_t)r * NK + 48] = acc3[r];
    }
}

// fast tanh: 1 - 2/(exp(2x)+1); safe at +-inf of exp
__device__ __forceinline__ float ftanh(float x) {
    float e = __expf(2.f * x);
    return 1.f - 2.f * __builtin_amdgcn_rcpf(e + 1.f);
}

// ---------------------------------------------------------------------------
// Kernel 2: per-(b,t) scores + softmaxes. One wave per row (b,t). (unchanged)
// ---------------------------------------------------------------------------
__global__ __launch_bounds__(256) void zab_kernel(
    const float* __restrict__ pg, const float* __restrict__ ps,
    const float* __restrict__ pv, const float* __restrict__ Wh,
    float* __restrict__ alpha, float* __restrict__ beta)
{
    int w = threadIdx.x >> 6, lane = threadIdx.x & 63;
    int row = blockIdx.x * 4 + w;        // 0..32767
    int b = row >> 9;

    const float* pgrow = pg + (size_t)row * NK;
    const float* psrow = ps + (size_t)row * NK;

    // phase A: z_ext
    float va = 0.f;
    if (lane < NK)
        va = ftanh(psrow[lane] + pgrow[lane]) * Wh[lane];
    float z_ext = va;
    #pragma unroll
    for (int off = 32; off; off >>= 1) z_ext += __shfl_xor(z_ext, off);

    // phase B: z[k]
    float z = -1e30f;
    if (lane < NK) {
        const float* pvrow = pv + ((size_t)b * NK + lane) * NK;
        float acc = 0.f;
        for (int j = 0; j < NK; j++)
            acc = fmaf(ftanh(pvrow[j] + pgrow[j]), Wh[j], acc);
        z = acc;
    }

    // softmax over k (49)
    float m = z;
    #pragma unroll
    for (int off = 32; off; off >>= 1) m = fmaxf(m, __shfl_xor(m, off));
    float p = (lane < NK) ? __expf(z - m) : 0.f;
    float ssum = p;
    #pragma unroll
    for (int off = 32; off; off >>= 1) ssum += __shfl_xor(ssum, off);
    float a = p * __builtin_amdgcn_rcpf(ssum);

    if (lane < NK)
        alpha[(size_t)row * NK + lane] = a;

    // extended softmax -> beta
    float me = fmaxf(m, z_ext);
    float se = ssum * __expf(m - me) + __expf(z_ext - me);
    float bet = __expf(z_ext - me) * __builtin_amdgcn_rcpf(se);
    if (lane == 0) beta[row] = bet;
}

// ---------------------------------------------------------------------------
// Kernel 3: c_hat = beta*sent + (1-beta)*(alpha @ V). (unchanged)
// ---------------------------------------------------------------------------
__global__ __launch_bounds__(256) void chat_kernel(
    const float* __restrict__ V, const float* __restrict__ sent,
    const float* __restrict__ alpha, const float* __restrict__ beta,
    float* __restrict__ chat)
{
    int d0 = blockIdx.x * 128;
    int t0 = blockIdx.y * 32;
    int b  = blockIdx.z;

    __shared__ float alpha_s[NK][36];   // transposed: [k][t], stride 36
    __shared__ float beta_s[32];

    int tid = threadIdx.x;

    const float* arow = alpha + ((size_t)b * NT + t0) * NK;  // 1568 contiguous
    for (int i = tid; i < 32 * NK; i += 256) {
        int t = i / NK, k = i - t * NK;
        alpha_s[k][t] = arow[i];
    }
    if (tid < 32) beta_s[tid] = beta[(size_t)b * NT + t0 + tid];
    __syncthreads();

    int tx = tid & 31;          // d-group: d = d0 + tx*4
    int ty = tid >> 5;          // t-group: t = t0 + ty*4 + i

    const float* vp = V + (size_t)b * NK * HIDDEN + d0 + tx * 4;

    float4 acc[4];
    #pragma unroll
    for (int i = 0; i < 4; i++) acc[i] = make_float4(0.f, 0.f, 0.f, 0.f);

    #pragma unroll 7
    for (int k = 0; k < NK; k++) {
        float4 vv = *(const float4*)(vp + (size_t)k * HIDDEN);
        float4 a4 = *(const float4*)&alpha_s[k][ty * 4];
        acc[0].x = fmaf(a4.x, vv.x, acc[0].x);
        acc[0].y = fmaf(a4.x, vv.y, acc[0].y);
        acc[0].z = fmaf(a4.x, vv.z, acc[0].z);
        acc[0].w = fmaf(a4.x, vv.w, acc[0].w);
        acc[1].x = fmaf(a4.y, vv.x, acc[1].x);
        acc[1].y = fmaf(a4.y, vv.y, acc[1].y);
        acc[1].z = fmaf(a4.y, vv.z, acc[1].z);
        acc[1].w = fmaf(a4.y, vv.w, acc[1].w);
        acc[2].x = fmaf(a4.z, vv.x, acc[2].x);
        acc[2].y = fmaf(a4.z, vv.y, acc[2].y);
        acc[2].z = fmaf(a4.z, vv.z, acc[2].z);
        acc[2].w = fmaf(a4.z, vv.w, acc[2].w);
        acc[3].x = fmaf(a4.w, vv.x, acc[3].x);
        acc[3].y = fmaf(a4.w, vv.y, acc[3].y);
        acc[3].z = fmaf(a4.w, vv.z, acc[3].z);
        acc[3].w = fmaf(a4.w, vv.w, acc[3].w);
    }

    #pragma unroll
    for (int i = 0; i < 4; i++) {
        int t = ty * 4 + i;
        float bt = beta_s[t];
        const float* sp = sent + ((size_t)b * NT + t0 + t) * HIDDEN + d0 + tx * 4;
        float*       op = chat + ((size_t)b * NT + t0 + t) * HIDDEN + d0 + tx * 4;
        float4 sv = *(const float4*)sp;
        float4 o;
        o.x = fmaf(bt, sv.x, (1.f - bt) * acc[i].x);
        o.y = fmaf(bt, sv.y, (1.f - bt) * acc[i].y);
        o.z = fmaf(bt, sv.z, (1.f - bt) * acc[i].z);
        o.w = fmaf(bt, sv.w, (1.f - bt) * acc[i].w);
        *(float4*)op = o;
    }
}

extern "C" void kernel_launch(void* const* d_in, const int* in_sizes, int n_in,
                              void* d_out, int out_size, void* d_ws, size_t ws_size,
                              hipStream_t stream)
{
    const float* V    = (const float*)d_in[0];
    const float* h_t  = (const float*)d_in[1];
    const float* sent = (const float*)d_in[2];
    const float* Wv   = (const float*)d_in[3];
    const float* Wg   = (const float*)d_in[4];
    const float* Ws   = (const float*)d_in[5];
    const float* Wh   = (const float*)d_in[6];

    float* out   = (float*)d_out;
    float* chat  = out;                                   // B*T*HIDDEN
    float* alpha = out + (size_t)NB * NT * HIDDEN;        // B*T*K
    float* beta  = alpha + (size_t)NB * NT * NK;          // B*T

    float* ws = (float*)d_ws;
    float* pg = ws;                                       // 32768*49
    float* ps = pg + (size_t)NB * NT * NK;                // 32768*49
    float* pv = ps + (size_t)NB * NT * NK;                // 3136*49
    unsigned short* Wf = (unsigned short*)(pv + (size_t)NB * NK * NK); // 3*16384*8 bf16

    convert_w<<<192, 256, 0, stream>>>(Wg, Ws, Wv, Wf);
    gemm_mfma<<<1073, 256, 0, stream>>>(h_t, sent, V, Wf, pg, ps, pv);
    zab_kernel<<<(NB * NT) / 4, 256, 0, stream>>>(pg, ps, pv, Wh, alpha, beta);
    chat_kernel<<<dim3(HIDDEN / 128, NT / 32, NB), 256, 0, stream>>>(V, sent, alpha, beta, chat);
}